// Round 2
// baseline (107.171 us; speedup 1.0000x reference)
//
#include <hip/hip_runtime.h>

// BilinearFullSymLoss: B=32 samples, grid [B,2,512,512] fp32.
// Per sample: masked sum of (delta0*sy + delta1*sx)^2 / count, then mean over B.
// Mask excludes the jnp.roll wrap region -> plain offset loads, no wrapping.
// neg branch simplified: d_neg = fx*a2 + (1-fx)*a1 - fy*s_top - (1-fy)*s_bot.
//
// Two-stage reduction (no atomics, no memset): stage 1 writes one scaled
// partial per block to d_ws; stage 2 sums the partials into d_out[0].

#define GH 512
#define GW 512
#define GB 32
#define ROWS_PER_BLOCK 8
#define BLOCK 256
#define NBLK_X ((GH + ROWS_PER_BLOCK - 1) / ROWS_PER_BLOCK)   // 64
#define NPART (NBLK_X * GB)                                    // 2048

__global__ __launch_bounds__(BLOCK) void bilinear_sym_loss_stage1(
    const float* __restrict__ grid,
    const float* __restrict__ gt,   // [B,2]  (gt_x, gt_y)
    const float* __restrict__ gd,   // [B,2]  (sx, sy)
    float* __restrict__ partials)
{
    const int b = blockIdx.z;

    // Per-sample scalars (wave-uniform)
    const float dx = -10.0f * gt[b * 2 + 0];
    const float dy =  10.0f * gt[b * 2 + 1];
    const float sx = gd[b * 2 + 0];
    const float sy = gd[b * 2 + 1];

    const float dy1f = floorf(dy);
    const float dx1f = floorf(dx);
    const int dy1 = (int)dy1f;
    const int dx1 = (int)dx1f;
    const float fy = dy - dy1f;
    const float fx = dx - dx1f;

    const bool pos = dx > 0.0f;
    const int rows = GH - dy1 - 1;
    const int cols = pos ? (GW - dx1 - 1) : (GW + dx1);

    const float w22 = fx * fy;
    const float w21 = fx * (1.0f - fy);
    const float w12 = (1.0f - fx) * fy;
    const float w11 = (1.0f - fx) * (1.0f - fy);

    const float* __restrict__ g0 = grid + (size_t)b * 2u * GH * GW;
    const float* __restrict__ g1 = g0 + GH * GW;

    const int tid = threadIdx.x;
    const int row0 = blockIdx.x * ROWS_PER_BLOCK;

    float acc = 0.0f;

    for (int r = 0; r < ROWS_PER_BLOCK; ++r) {
        const int i = row0 + r;
        if (i >= rows) break;  // uniform across block

        if (pos) {
            // delta = g[i,j] - (w11*g[i+dy1, j+dx1]   + w21*g[i+dy1, j+dx1+1]
            //                 + w12*g[i+dy1+1, j+dx1] + w22*g[i+dy1+1, j+dx1+1])
            const float* r0c  = g0 + i * GW;
            const float* r0a  = g0 + (i + dy1) * GW + dx1;
            const float* r0b  = g0 + (i + dy1 + 1) * GW + dx1;
            const float* r1c  = g1 + i * GW;
            const float* r1a  = g1 + (i + dy1) * GW + dx1;
            const float* r1b  = g1 + (i + dy1 + 1) * GW + dx1;
            for (int j = tid; j < cols; j += BLOCK) {
                float interp0 = w11 * r0a[j];
                interp0 = fmaf(w21, r0a[j + 1], interp0);
                interp0 = fmaf(w12, r0b[j], interp0);
                interp0 = fmaf(w22, r0b[j + 1], interp0);
                const float d0 = r0c[j] - interp0;

                float interp1 = w11 * r1a[j];
                interp1 = fmaf(w21, r1a[j + 1], interp1);
                interp1 = fmaf(w12, r1b[j], interp1);
                interp1 = fmaf(w22, r1b[j + 1], interp1);
                const float d1 = r1c[j] - interp1;

                const float val = fmaf(d0, sy, d1 * sx);
                acc = fmaf(val, val, acc);
            }
        } else {
            // d_neg = fx*g[i+dy1+1, j+1] + (1-fx)*g[i+dy1+1, j]
            //       - fy*g[i, j-dx1]     - (1-fy)*g[i+1, j-dx1]
            const float omfx = 1.0f - fx;
            const float omfy = 1.0f - fy;
            const int jo = -dx1;  // positive shift
            const float* r0a = g0 + (i + dy1 + 1) * GW;   // a1 at [j], a2 at [j+1]
            const float* r0t = g0 + i * GW + jo;          // s_top
            const float* r0s = g0 + (i + 1) * GW + jo;    // s_bot
            const float* r1a = g1 + (i + dy1 + 1) * GW;
            const float* r1t = g1 + i * GW + jo;
            const float* r1s = g1 + (i + 1) * GW + jo;
            for (int j = tid; j < cols; j += BLOCK) {
                float d0 = fx * r0a[j + 1];
                d0 = fmaf(omfx, r0a[j], d0);
                d0 = fmaf(-fy, r0t[j], d0);
                d0 = fmaf(-omfy, r0s[j], d0);

                float d1 = fx * r1a[j + 1];
                d1 = fmaf(omfx, r1a[j], d1);
                d1 = fmaf(-fy, r1t[j], d1);
                d1 = fmaf(-omfy, r1s[j], d1);

                const float val = fmaf(d0, sy, d1 * sx);
                acc = fmaf(val, val, acc);
            }
        }
    }

    // Block reduction: wave64 shuffle, then LDS across the 4 waves.
    for (int off = 32; off > 0; off >>= 1)
        acc += __shfl_down(acc, off, 64);

    __shared__ float wave_sums[BLOCK / 64];
    const int lane = tid & 63;
    const int wid = tid >> 6;
    if (lane == 0) wave_sums[wid] = acc;
    __syncthreads();

    if (tid == 0) {
        float s = wave_sums[0] + wave_sums[1] + wave_sums[2] + wave_sums[3];
        const float count = (float)rows * (float)cols;
        const float scale = 1.0f / (count * (float)GB);
        // Every block writes (covers the 0xAA poison in d_ws).
        partials[b * NBLK_X + blockIdx.x] = s * scale;
    }
}

__global__ __launch_bounds__(BLOCK) void bilinear_sym_loss_stage2(
    const float* __restrict__ partials,
    float* __restrict__ out)
{
    const int tid = threadIdx.x;
    float acc = 0.0f;
    for (int i = tid; i < NPART; i += BLOCK)
        acc += partials[i];

    for (int off = 32; off > 0; off >>= 1)
        acc += __shfl_down(acc, off, 64);

    __shared__ float wave_sums[BLOCK / 64];
    const int lane = tid & 63;
    const int wid = tid >> 6;
    if (lane == 0) wave_sums[wid] = acc;
    __syncthreads();

    if (tid == 0)
        out[0] = wave_sums[0] + wave_sums[1] + wave_sums[2] + wave_sums[3];
}

extern "C" void kernel_launch(void* const* d_in, const int* in_sizes, int n_in,
                              void* d_out, int out_size, void* d_ws, size_t ws_size,
                              hipStream_t stream) {
    const float* grid = (const float*)d_in[0];
    const float* gt   = (const float*)d_in[1];
    const float* gd   = (const float*)d_in[2];
    float* out = (float*)d_out;
    float* partials = (float*)d_ws;  // NPART floats = 8 KiB, well within ws

    dim3 grid1(NBLK_X, 1, GB);
    bilinear_sym_loss_stage1<<<grid1, dim3(BLOCK), 0, stream>>>(grid, gt, gd, partials);
    bilinear_sym_loss_stage2<<<dim3(1), dim3(BLOCK), 0, stream>>>(partials, out);
}

// Round 3
// 102.331 us; speedup vs baseline: 1.0473x; 1.0473x over previous
//
#include <hip/hip_runtime.h>

// BilinearFullSymLoss: B=32 samples, grid [B,2,512,512] fp32.
// Per sample: masked sum of (delta0*sy + delta1*sx)^2 / count, then mean over B.
// Mask excludes the jnp.roll wrap region -> plain offset loads, no wrapping.
// neg branch simplified: d_neg = fx*a2 + (1-fx)*a1 - fy*s_top - (1-fy)*s_bot.
//
// Round 3: vectorized 4-wide loads. Center/anchor rows are 16B-aligned float4;
// column-shifted rows use align(4) 16B loads (gfx9+ allows dword-aligned
// dwordx4). 128 lanes cover one row's ~127 groups; block sweeps 2 rows/pass.

#define GH 512
#define GW 512
#define GB 32
#define CH (GH * GW)
#define ROWS_PER_BLOCK 8
#define BLOCK 256
#define NBLK_X ((GH + ROWS_PER_BLOCK - 1) / ROWS_PER_BLOCK)   // 64
#define NPART (NBLK_X * GB)                                    // 2048

struct F4U { float x, y, z, w; };  // natural align = 4 -> unaligned-capable 16B load

__device__ __forceinline__ F4U ld4u(const float* p) {
    return *(const F4U*)p;
}

// pos branch, one channel, 4 elements at j0:
// d[k] = c[j0+k] - (w11*a[j0+k] + w21*a[j0+k+1] + w12*b[j0+k] + w22*b[j0+k+1])
__device__ __forceinline__ void interp4_pos(
    const float* __restrict__ rc, const float* __restrict__ ra,
    const float* __restrict__ rb, int j0,
    float w11, float w21, float w12, float w22, float d[4])
{
    const float4 c = *(const float4*)(rc + j0);   // aligned
    const F4U A = ld4u(ra + j0);
    const float a4 = ra[j0 + 4];
    const F4U Bv = ld4u(rb + j0);
    const float b4 = rb[j0 + 4];

    float t;
    t = w11 * A.x; t = fmaf(w21, A.y, t); t = fmaf(w12, Bv.x, t); t = fmaf(w22, Bv.y, t);
    d[0] = c.x - t;
    t = w11 * A.y; t = fmaf(w21, A.z, t); t = fmaf(w12, Bv.y, t); t = fmaf(w22, Bv.z, t);
    d[1] = c.y - t;
    t = w11 * A.z; t = fmaf(w21, A.w, t); t = fmaf(w12, Bv.z, t); t = fmaf(w22, Bv.w, t);
    d[2] = c.z - t;
    t = w11 * A.w; t = fmaf(w21, a4, t);  t = fmaf(w12, Bv.w, t); t = fmaf(w22, b4, t);
    d[3] = c.w - t;
}

// neg branch, one channel, 4 elements at j0:
// d[k] = fx*a[j0+k+1] + (1-fx)*a[j0+k] - fy*t[j0+k] - (1-fy)*s[j0+k]
__device__ __forceinline__ void interp4_neg(
    const float* __restrict__ ra, const float* __restrict__ rt,
    const float* __restrict__ rs, int j0,
    float fx, float omfx, float fy, float omfy, float d[4])
{
    const float4 A = *(const float4*)(ra + j0);   // aligned (no col offset)
    const float a4 = ra[j0 + 4];
    const F4U T = ld4u(rt + j0);
    const F4U S = ld4u(rs + j0);

    float t;
    t = fx * A.y; t = fmaf(omfx, A.x, t); t = fmaf(-fy, T.x, t); t = fmaf(-omfy, S.x, t);
    d[0] = t;
    t = fx * A.z; t = fmaf(omfx, A.y, t); t = fmaf(-fy, T.y, t); t = fmaf(-omfy, S.y, t);
    d[1] = t;
    t = fx * A.w; t = fmaf(omfx, A.z, t); t = fmaf(-fy, T.z, t); t = fmaf(-omfy, S.z, t);
    d[2] = t;
    t = fx * a4;  t = fmaf(omfx, A.w, t); t = fmaf(-fy, T.w, t); t = fmaf(-omfy, S.w, t);
    d[3] = t;
}

__global__ __launch_bounds__(BLOCK) void bilinear_sym_loss_stage1(
    const float* __restrict__ grid,
    const float* __restrict__ gt,   // [B,2]  (gt_x, gt_y)
    const float* __restrict__ gd,   // [B,2]  (sx, sy)
    float* __restrict__ partials)
{
    const int b = blockIdx.z;

    const float dx = -10.0f * gt[b * 2 + 0];
    const float dy =  10.0f * gt[b * 2 + 1];
    const float sx = gd[b * 2 + 0];
    const float sy = gd[b * 2 + 1];

    const float dy1f = floorf(dy);
    const float dx1f = floorf(dx);
    const int dy1 = (int)dy1f;
    const int dx1 = (int)dx1f;
    const float fy = dy - dy1f;
    const float fx = dx - dx1f;

    const bool pos = dx > 0.0f;
    const int rows = GH - dy1 - 1;
    const int cols = pos ? (GW - dx1 - 1) : (GW + dx1);   // 507..509 always
    const int ng4 = cols >> 2;                             // <= 127
    const int rem = cols & 3;
    const int jt0 = ng4 << 2;

    const float w22 = fx * fy;
    const float w21 = fx * (1.0f - fy);
    const float w12 = (1.0f - fx) * fy;
    const float w11 = (1.0f - fx) * (1.0f - fy);
    const float omfx = 1.0f - fx;
    const float omfy = 1.0f - fy;

    const float* __restrict__ g0 = grid + (size_t)b * 2u * CH;

    const int tid = threadIdx.x;
    const int g = tid & 127;     // group index within row
    const int half = tid >> 7;   // which of the 2 rows this pass (wave-uniform)
    const int row0 = blockIdx.x * ROWS_PER_BLOCK;

    float acc = 0.0f;

    if (pos) {
        for (int rp = 0; rp < ROWS_PER_BLOCK; rp += 2) {
            const int i = row0 + rp + half;
            if (i >= rows) continue;   // uniform per half (per wave-pair)

            const float* r0c = g0 + i * GW;
            const float* r0a = g0 + (i + dy1) * GW + dx1;
            const float* r0b = r0a + GW;
            const float* r1c = r0c + CH;
            const float* r1a = r0a + CH;
            const float* r1b = r0b + CH;

            if (g < ng4) {
                const int j0 = g << 2;
                float d0[4], d1[4];
                interp4_pos(r0c, r0a, r0b, j0, w11, w21, w12, w22, d0);
                interp4_pos(r1c, r1a, r1b, j0, w11, w21, w12, w22, d1);
                #pragma unroll
                for (int k = 0; k < 4; ++k) {
                    const float val = fmaf(d0[k], sy, d1[k] * sx);
                    acc = fmaf(val, val, acc);
                }
            }
            if (g < rem) {
                const int j = jt0 + g;
                float t0 = w11 * r0a[j];
                t0 = fmaf(w21, r0a[j + 1], t0);
                t0 = fmaf(w12, r0b[j], t0);
                t0 = fmaf(w22, r0b[j + 1], t0);
                const float e0 = r0c[j] - t0;
                float t1 = w11 * r1a[j];
                t1 = fmaf(w21, r1a[j + 1], t1);
                t1 = fmaf(w12, r1b[j], t1);
                t1 = fmaf(w22, r1b[j + 1], t1);
                const float e1 = r1c[j] - t1;
                const float val = fmaf(e0, sy, e1 * sx);
                acc = fmaf(val, val, acc);
            }
        }
    } else {
        const int jo = -dx1;   // 3..5
        for (int rp = 0; rp < ROWS_PER_BLOCK; rp += 2) {
            const int i = row0 + rp + half;
            if (i >= rows) continue;

            const float* r0a = g0 + (i + dy1 + 1) * GW;   // a1 at [j], a2 at [j+1]
            const float* r0t = g0 + i * GW + jo;          // s_top
            const float* r0s = r0t + GW;                  // s_bot
            const float* r1a = r0a + CH;
            const float* r1t = r0t + CH;
            const float* r1s = r0s + CH;

            if (g < ng4) {
                const int j0 = g << 2;
                float d0[4], d1[4];
                interp4_neg(r0a, r0t, r0s, j0, fx, omfx, fy, omfy, d0);
                interp4_neg(r1a, r1t, r1s, j0, fx, omfx, fy, omfy, d1);
                #pragma unroll
                for (int k = 0; k < 4; ++k) {
                    const float val = fmaf(d0[k], sy, d1[k] * sx);
                    acc = fmaf(val, val, acc);
                }
            }
            if (g < rem) {
                const int j = jt0 + g;
                float e0 = fx * r0a[j + 1];
                e0 = fmaf(omfx, r0a[j], e0);
                e0 = fmaf(-fy, r0t[j], e0);
                e0 = fmaf(-omfy, r0s[j], e0);
                float e1 = fx * r1a[j + 1];
                e1 = fmaf(omfx, r1a[j], e1);
                e1 = fmaf(-fy, r1t[j], e1);
                e1 = fmaf(-omfy, r1s[j], e1);
                const float val = fmaf(e0, sy, e1 * sx);
                acc = fmaf(val, val, acc);
            }
        }
    }

    // Block reduction: wave64 shuffle, then LDS across the 4 waves.
    for (int off = 32; off > 0; off >>= 1)
        acc += __shfl_down(acc, off, 64);

    __shared__ float wave_sums[BLOCK / 64];
    const int lane = tid & 63;
    const int wid = tid >> 6;
    if (lane == 0) wave_sums[wid] = acc;
    __syncthreads();

    if (tid == 0) {
        float s = wave_sums[0] + wave_sums[1] + wave_sums[2] + wave_sums[3];
        const float count = (float)rows * (float)cols;
        const float scale = 1.0f / (count * (float)GB);
        partials[b * NBLK_X + blockIdx.x] = s * scale;   // covers ws poison
    }
}

__global__ __launch_bounds__(BLOCK) void bilinear_sym_loss_stage2(
    const float* __restrict__ partials,
    float* __restrict__ out)
{
    const int tid = threadIdx.x;
    float acc = 0.0f;
    for (int i = tid; i < NPART; i += BLOCK)
        acc += partials[i];

    for (int off = 32; off > 0; off >>= 1)
        acc += __shfl_down(acc, off, 64);

    __shared__ float wave_sums[BLOCK / 64];
    const int lane = tid & 63;
    const int wid = tid >> 6;
    if (lane == 0) wave_sums[wid] = acc;
    __syncthreads();

    if (tid == 0)
        out[0] = wave_sums[0] + wave_sums[1] + wave_sums[2] + wave_sums[3];
}

extern "C" void kernel_launch(void* const* d_in, const int* in_sizes, int n_in,
                              void* d_out, int out_size, void* d_ws, size_t ws_size,
                              hipStream_t stream) {
    const float* grid = (const float*)d_in[0];
    const float* gt   = (const float*)d_in[1];
    const float* gd   = (const float*)d_in[2];
    float* out = (float*)d_out;
    float* partials = (float*)d_ws;  // NPART floats = 8 KiB

    dim3 grid1(NBLK_X, 1, GB);
    bilinear_sym_loss_stage1<<<grid1, dim3(BLOCK), 0, stream>>>(grid, gt, gd, partials);
    bilinear_sym_loss_stage2<<<dim3(1), dim3(BLOCK), 0, stream>>>(partials, out);
}

// Round 4
// 98.709 us; speedup vs baseline: 1.0857x; 1.0367x over previous
//
#include <hip/hip_runtime.h>

// BilinearFullSymLoss: B=32 samples, grid [B,2,512,512] fp32.
// Per sample: masked sum of (delta0*sy + delta1*sx)^2 / count, then mean over B.
// Mask excludes the jnp.roll wrap region -> plain offset loads, no wrapping.
// neg branch simplified: d_neg = fx*a2 + (1-fx)*a1 - fy*s_top - (1-fy)*s_bot.
//
// Round 4: register row-chaining (pos: b(i)=a(i+1); neg: s_bot(i)=s_top(i+1))
// -> 0.72 VMEM instr/element; uniform control flow (tail chunk re-anchored at
// cols-8 with cndmask on duplicated elements). Block = 16 rows x 512 cols.

#define GH 512
#define GW 512
#define GB 32
#define CH (GH * GW)
#define RPB 16
#define BLOCK 256
#define NBLK_X (GH / RPB)        // 32
#define NPART (NBLK_X * GB)      // 1024

struct F4U { float x, y, z, w; };   // align 4 -> dword-aligned 16B loads ok

__device__ __forceinline__ void load9(const float* __restrict__ p, float* o) {
    const F4U a = *(const F4U*)p;
    const F4U b = *(const F4U*)(p + 4);
    o[0]=a.x; o[1]=a.y; o[2]=a.z; o[3]=a.w;
    o[4]=b.x; o[5]=b.y; o[6]=b.z; o[7]=b.w;
    o[8] = p[8];
}

__device__ __forceinline__ void load8(const float* __restrict__ p, float* o) {
    const F4U a = *(const F4U*)p;
    const F4U b = *(const F4U*)(p + 4);
    o[0]=a.x; o[1]=a.y; o[2]=a.z; o[3]=a.w;
    o[4]=b.x; o[5]=b.y; o[6]=b.z; o[7]=b.w;
}

__global__ __launch_bounds__(BLOCK) void bilinear_sym_loss_stage1(
    const float* __restrict__ grid,
    const float* __restrict__ gt,   // [B,2]  (gt_x, gt_y)
    const float* __restrict__ gd,   // [B,2]  (sx, sy)
    float* __restrict__ partials)
{
    const int b = blockIdx.y;

    const float dx = -10.0f * gt[b * 2 + 0];
    const float dy =  10.0f * gt[b * 2 + 1];
    const float sx = gd[b * 2 + 0];
    const float sy = gd[b * 2 + 1];

    const float dy1f = floorf(dy);
    const float dx1f = floorf(dx);
    const int dy1 = (int)dy1f;
    const int dx1 = (int)dx1f;
    const float fy = dy - dy1f;
    const float fx = dx - dx1f;

    const bool pos = dx > 0.0f;
    const int rows = GH - dy1 - 1;                        // 506..511
    const int cols = pos ? (GW - dx1 - 1) : (GW + dx1);   // 507..509

    const float omfx = 1.0f - fx;
    const float omfy = 1.0f - fy;
    const float w22 = fx * fy;
    const float w21 = fx * omfy;
    const float w12 = omfx * fy;
    const float w11 = omfx * omfy;

    const float* __restrict__ g0 = grid + (size_t)b * 2u * CH;

    const int tid = threadIdx.x;
    const int cc = tid & 63;          // column chunk (8 cols each)
    const int rg = tid >> 6;          // row group (wave-uniform)
    const int i0 = blockIdx.x * RPB + rg * 4;

    // Last chunk re-anchors at cols-8; kmin masks elements already counted
    // by the previous chunk. All lanes then run identical vector code.
    int j0 = cc << 3;
    int kmin = 0;
    if (j0 > cols - 8) { kmin = j0 - (cols - 8); j0 = cols - 8; }

    float acc = 0.0f;

    if (pos) {
        if (i0 < rows) {   // wave-uniform
            const float* pa0 = g0 + (i0 + dy1) * GW + dx1 + j0;   // shifted rows, ch0
            const float* pc0 = g0 + i0 * GW + j0;                 // center rows, ch0
            float P0[9], P1[9];
            load9(pa0, P0);
            load9(pa0 + CH, P1);
            #pragma unroll
            for (int r = 0; r < 4; ++r) {
                const int i = i0 + r;
                if (i >= rows) break;   // wave-uniform
                float B0[9], B1[9], C0[8], C1[8];
                load9(pa0 + (r + 1) * GW, B0);
                load9(pa0 + (r + 1) * GW + CH, B1);
                load8(pc0 + r * GW, C0);
                load8(pc0 + r * GW + CH, C1);
                #pragma unroll
                for (int k = 0; k < 8; ++k) {
                    float t0 = w11 * P0[k];
                    t0 = fmaf(w21, P0[k + 1], t0);
                    t0 = fmaf(w12, B0[k], t0);
                    t0 = fmaf(w22, B0[k + 1], t0);
                    const float d0 = C0[k] - t0;
                    float t1 = w11 * P1[k];
                    t1 = fmaf(w21, P1[k + 1], t1);
                    t1 = fmaf(w12, B1[k], t1);
                    t1 = fmaf(w22, B1[k + 1], t1);
                    const float d1 = C1[k] - t1;
                    float v = fmaf(d0, sy, d1 * sx);
                    v = (k >= kmin) ? v : 0.0f;
                    acc = fmaf(v, v, acc);
                }
                #pragma unroll
                for (int k = 0; k < 9; ++k) { P0[k] = B0[k]; P1[k] = B1[k]; }
            }
        }
    } else {
        if (i0 < rows) {
            const int jo = -dx1;   // 3..5
            const float* pt0 = g0 + i0 * GW + jo + j0;             // s_top row for i0
            const float* pa0 = g0 + (i0 + dy1 + 1) * GW + j0;      // anchor rows
            float T0[8], T1[8];
            load8(pt0, T0);
            load8(pt0 + CH, T1);
            #pragma unroll
            for (int r = 0; r < 4; ++r) {
                const int i = i0 + r;
                if (i >= rows) break;
                float S0[8], S1[8], A0[9], A1[9];
                load8(pt0 + (r + 1) * GW, S0);
                load8(pt0 + (r + 1) * GW + CH, S1);
                load9(pa0 + r * GW, A0);
                load9(pa0 + r * GW + CH, A1);
                #pragma unroll
                for (int k = 0; k < 8; ++k) {
                    float d0 = fx * A0[k + 1];
                    d0 = fmaf(omfx, A0[k], d0);
                    d0 = fmaf(-fy, T0[k], d0);
                    d0 = fmaf(-omfy, S0[k], d0);
                    float d1 = fx * A1[k + 1];
                    d1 = fmaf(omfx, A1[k], d1);
                    d1 = fmaf(-fy, T1[k], d1);
                    d1 = fmaf(-omfy, S1[k], d1);
                    float v = fmaf(d0, sy, d1 * sx);
                    v = (k >= kmin) ? v : 0.0f;
                    acc = fmaf(v, v, acc);
                }
                #pragma unroll
                for (int k = 0; k < 8; ++k) { T0[k] = S0[k]; T1[k] = S1[k]; }
            }
        }
    }

    // Block reduction: wave64 shuffle, then LDS across the 4 waves.
    for (int off = 32; off > 0; off >>= 1)
        acc += __shfl_down(acc, off, 64);

    __shared__ float wave_sums[BLOCK / 64];
    const int lane = tid & 63;
    const int wid = tid >> 6;
    if (lane == 0) wave_sums[wid] = acc;
    __syncthreads();

    if (tid == 0) {
        const float s = wave_sums[0] + wave_sums[1] + wave_sums[2] + wave_sums[3];
        const float count = (float)rows * (float)cols;
        const float scale = 1.0f / (count * (float)GB);
        partials[b * NBLK_X + blockIdx.x] = s * scale;   // covers ws poison
    }
}

__global__ __launch_bounds__(BLOCK) void bilinear_sym_loss_stage2(
    const float* __restrict__ partials,
    float* __restrict__ out)
{
    const int tid = threadIdx.x;
    float acc = 0.0f;
    for (int i = tid; i < NPART; i += BLOCK)
        acc += partials[i];

    for (int off = 32; off > 0; off >>= 1)
        acc += __shfl_down(acc, off, 64);

    __shared__ float wave_sums[BLOCK / 64];
    const int lane = tid & 63;
    const int wid = tid >> 6;
    if (lane == 0) wave_sums[wid] = acc;
    __syncthreads();

    if (tid == 0)
        out[0] = wave_sums[0] + wave_sums[1] + wave_sums[2] + wave_sums[3];
}

extern "C" void kernel_launch(void* const* d_in, const int* in_sizes, int n_in,
                              void* d_out, int out_size, void* d_ws, size_t ws_size,
                              hipStream_t stream) {
    const float* grid = (const float*)d_in[0];
    const float* gt   = (const float*)d_in[1];
    const float* gd   = (const float*)d_in[2];
    float* out = (float*)d_out;
    float* partials = (float*)d_ws;  // NPART floats = 4 KiB

    dim3 grid1(NBLK_X, GB);
    bilinear_sym_loss_stage1<<<grid1, dim3(BLOCK), 0, stream>>>(grid, gt, gd, partials);
    bilinear_sym_loss_stage2<<<dim3(1), dim3(BLOCK), 0, stream>>>(partials, out);
}